// Round 2
// baseline (177.366 us; speedup 1.0000x reference)
//
#include <hip/hip_runtime.h>

// HQQ 4-bit dequant + linear (Llama-7B up-proj, decode: 8 tokens)
// OUT=11008, IN=4096, GS=64, G=704512, OC=172 (=G/IN; OUT=64*OC)
// W_q: [32, G] int32 (one byte per word: hi nibble -> unpacked row rq,
//      lo nibble -> row rq+32 of the [64, G] tensor)
// Mapping: W_r[o, i] with r=o/172, oc=o%172, g=oc*4096+i  (scale/zero are
// contiguous in K for fixed o; each packed word serves TWO output rows).
// out[b, o] = sum_i x[b,i] * ((nib - zero[g]) * scale[g]) + bias[o]
//           = sum_i x[b,i] * fma(nib, s[g], -z[g]*s[g]) + bias[o]
//
// R2: split-K x2 (atomicAdd into zero-inited out) -> 1376 blocks, 5.4
// waves/SIMD avg; explicit prefetch of the two cold Wq int4 streams;
// x/scale/zero left to L2 (each x element has 688 readers -> L2-hot);
// b-loop loads x just-in-time to keep VGPR < 128 (launch_bounds(256,4)).

#define OUT_ 11008
#define IN_ 4096
#define G_ 704512
#define OC_ 172

__global__ void zero_out_kernel(float* __restrict__ out) {
    const int t = blockIdx.x * 256 + threadIdx.x;
    if (t < 8 * OUT_) out[t] = 0.f;
}

__global__ __launch_bounds__(256, 4)
void hqq_gemv(const int* __restrict__ Wq, const float* __restrict__ scale,
              const float* __restrict__ zero, const float* __restrict__ x,
              const float* __restrict__ bias, float* __restrict__ out) {
    const int lane = threadIdx.x;             // 0..63 : K-slice within 256-chunk
    const int ty   = threadIdx.y;             // 0..3  : row sub-group
    const int oc   = blockIdx.y;              // 0..171
    const int ks   = blockIdx.z;              // 0..1  : K-half
    const int rq0  = blockIdx.x * 8 + ty * 2; // packed rows rq0, rq0+1

    const int kbase = ks * (IN_ / 2);
    const long gb = (long)oc * IN_ + kbase;
    const int* __restrict__ wqA = Wq + (long)rq0 * G_ + gb;
    const int* __restrict__ wqB = wqA + G_;
    const float* __restrict__ sp = scale + gb;
    const float* __restrict__ zp = zero + gb;
    const float* __restrict__ xp = x + kbase;

    // acc[0]=hi of rq0, acc[1]=lo of rq0, acc[2]=hi of rq0+1, acc[3]=lo of rq0+1
    float acc[4][8];
#pragma unroll
    for (int r = 0; r < 4; ++r)
#pragma unroll
        for (int b = 0; b < 8; ++b) acc[r][b] = 0.f;

    int i = lane * 4;
    int4 qa = *(const int4*)(wqA + i);
    int4 qb = *(const int4*)(wqB + i);

#pragma unroll
    for (int it = 0; it < 8; ++it) {          // 8 x 256 = 2048 K per block
        const float4 s4 = *(const float4*)(sp + i);
        const float4 z4 = *(const float4*)(zp + i);
        int4 qa_n, qb_n;
        if (it < 7) {                          // prefetch the cold Wq streams
            qa_n = *(const int4*)(wqA + i + 256);
            qb_n = *(const int4*)(wqB + i + 256);
        }
        const float ss[4] = {s4.x, s4.y, s4.z, s4.w};
        const float zs[4] = {-z4.x * s4.x, -z4.y * s4.y, -z4.z * s4.z, -z4.w * s4.w};
        const int qsA[4] = {qa.x, qa.y, qa.z, qa.w};
        const int qsB[4] = {qb.x, qb.y, qb.z, qb.w};

        float w[4][4];                         // [hiA, loA, hiB, loB][j]
#pragma unroll
        for (int j = 0; j < 4; ++j) {
            w[0][j] = fmaf((float)((qsA[j] >> 4) & 0xF), ss[j], zs[j]);
            w[1][j] = fmaf((float)( qsA[j]       & 0xF), ss[j], zs[j]);
            w[2][j] = fmaf((float)((qsB[j] >> 4) & 0xF), ss[j], zs[j]);
            w[3][j] = fmaf((float)( qsB[j]       & 0xF), ss[j], zs[j]);
        }
#pragma unroll
        for (int b = 0; b < 8; ++b) {
            const float4 xb = *(const float4*)(xp + b * IN_ + i);
#pragma unroll
            for (int r = 0; r < 4; ++r) {
                float a = acc[r][b];
                a = fmaf(xb.x, w[r][0], a);
                a = fmaf(xb.y, w[r][1], a);
                a = fmaf(xb.z, w[r][2], a);
                a = fmaf(xb.w, w[r][3], a);
                acc[r][b] = a;
            }
        }
        if (it < 7) { qa = qa_n; qb = qb_n; }
        i += 256;
    }

    // reduce each accumulator across the 64 K-slice lanes
#pragma unroll
    for (int r = 0; r < 4; ++r)
#pragma unroll
        for (int b = 0; b < 8; ++b) {
            float v = acc[r][b];
#pragma unroll
            for (int off = 32; off > 0; off >>= 1)
                v += __shfl_down(v, off, 64);
            acc[r][b] = v;
        }

    if (lane == 0) {
        const int o[4] = {rq0 * OC_ + oc, (rq0 + 32) * OC_ + oc,
                          (rq0 + 1) * OC_ + oc, (rq0 + 33) * OC_ + oc};
#pragma unroll
        for (int r = 0; r < 4; ++r) {
            const float bb = (ks == 0) ? bias[o[r]] : 0.f;
#pragma unroll
            for (int b = 0; b < 8; ++b)
                atomicAdd(out + b * OUT_ + o[r], acc[r][b] + bb);
        }
    }
}

extern "C" void kernel_launch(void* const* d_in, const int* in_sizes, int n_in,
                              void* d_out, int out_size, void* d_ws, size_t ws_size,
                              hipStream_t stream) {
    const int*   Wq    = (const int*)d_in[0];    // [32, 704512] int32
    const float* scale = (const float*)d_in[1];  // [1, 704512]
    const float* zero  = (const float*)d_in[2];  // [1, 704512]
    const float* x     = (const float*)d_in[3];  // [8, 1, 4096]
    const float* bias  = (const float*)d_in[4];  // [11008]
    float* out = (float*)d_out;                  // [8, 1, 11008]

    zero_out_kernel<<<(8 * OUT_ + 255) / 256, 256, 0, stream>>>(out);

    dim3 grid(4, OC_, 2);   // x: rq-group (8 packed rows), y: oc, z: K-half
    dim3 block(64, 4);      // 64 lanes along K, 4 row sub-groups
    hqq_gemv<<<grid, block, 0, stream>>>(Wq, scale, zero, x, bias, out);
}

// Round 3
// 152.238 us; speedup vs baseline: 1.1651x; 1.1651x over previous
//
#include <hip/hip_runtime.h>

// HQQ 4-bit dequant + linear (Llama-7B up-proj, decode: 8 tokens)
// OUT=11008, IN=4096, GS=64, G=704512, OC=172 (=G/IN; OUT=64*OC)
// W_q: [32, G] int32 (one byte per word: hi nibble -> unpacked row rq,
//      lo nibble -> row rq+32 of the [64, G] tensor)
// Mapping: W_r[o, i] with r=o/172, oc=o%172, g=oc*4096+i.
// out[b, o] = sum_i x[b,i] * fma(nib, s[g], -z[g]*s[g]) + bias[o]
//
// R3 theory: R2 was latency-bound (854 GB/s = 10.7% peak, VALU 21%).
//  - x, scale, zero staged in LDS once per block (80 KB) -> K-loop's only
//    global traffic is the two cold Wq streams.
//  - Wq prefetched to FULL depth (8 iters x 2 streams of int4, all
//    independent, ~16 KB in flight per wave) -> MLP instead of waitcnt ladder.
//  - No atomics: split-K partials to d_ws, combined by reduce kernel.

#define OUT_ 11008
#define IN_ 4096
#define G_ 704512
#define OC_ 172
#define KS 2              // K-split factor
#define KC (IN_ / KS)     // 2048 K per block
#define ITERS (KC / 256)  // 8

__global__ __launch_bounds__(256, 2)
void hqq_gemv(const int* __restrict__ Wq, const float* __restrict__ scale,
              const float* __restrict__ zero, const float* __restrict__ x,
              float* __restrict__ ws) {
    __shared__ float s_lds[KC];
    __shared__ float z_lds[KC];
    __shared__ float x_lds[8 * KC];

    const int lane = threadIdx.x;              // 0..63
    const int ty   = threadIdx.y;              // 0..3
    const int tid  = ty * 64 + lane;           // 0..255
    const int oc   = blockIdx.y;               // 0..171
    const int ks   = blockIdx.z;               // 0..KS-1
    const int rq0  = blockIdx.x * 8 + ty * 2;  // packed rows rq0, rq0+1

    const int kbase = ks * KC;
    const long gb = (long)oc * IN_ + kbase;

    // ---- stage scale/zero (2 rounds each) and x (16 rounds) into LDS ----
#pragma unroll
    for (int r = 0; r < KC / 1024; ++r) {
        const int off = r * 1024 + tid * 4;
        *(float4*)(s_lds + off) = *(const float4*)(scale + gb + off);
        *(float4*)(z_lds + off) = *(const float4*)(zero + gb + off);
    }
#pragma unroll
    for (int r = 0; r < 8 * KC / 1024; ++r) {
        const int off = r * 1024 + tid * 4;    // linear over [b][k]
        const int b = off >> 11;               // off / KC
        const int k = off & (KC - 1);          // off % KC
        *(float4*)(x_lds + off) = *(const float4*)(x + b * IN_ + kbase + k);
    }

    // ---- prefetch ALL Wq for this wave: 16 independent dwordx4 ----
    const int* __restrict__ wqA = Wq + (long)rq0 * G_ + gb;
    const int* __restrict__ wqB = wqA + G_;
    int4 qA[ITERS], qB[ITERS];
#pragma unroll
    for (int it = 0; it < ITERS; ++it) {
        qA[it] = *(const int4*)(wqA + it * 256 + lane * 4);
        qB[it] = *(const int4*)(wqB + it * 256 + lane * 4);
    }

    __syncthreads();

    // acc[0]=hi(rq0) acc[1]=lo(rq0) acc[2]=hi(rq0+1) acc[3]=lo(rq0+1)
    float acc[4][8];
#pragma unroll
    for (int r = 0; r < 4; ++r)
#pragma unroll
        for (int b = 0; b < 8; ++b) acc[r][b] = 0.f;

#pragma unroll
    for (int it = 0; it < ITERS; ++it) {
        const int i = it * 256 + lane * 4;
        const float4 s4 = *(const float4*)(s_lds + i);
        const float4 z4 = *(const float4*)(z_lds + i);
        const float ss[4] = {s4.x, s4.y, s4.z, s4.w};
        const float zs[4] = {-z4.x * s4.x, -z4.y * s4.y, -z4.z * s4.z, -z4.w * s4.w};
        const int qsA[4] = {qA[it].x, qA[it].y, qA[it].z, qA[it].w};
        const int qsB[4] = {qB[it].x, qB[it].y, qB[it].z, qB[it].w};

        float w[4][4];  // [hiA, loA, hiB, loB][j]
#pragma unroll
        for (int j = 0; j < 4; ++j) {
            w[0][j] = fmaf((float)((qsA[j] >> 4) & 0xF), ss[j], zs[j]);
            w[1][j] = fmaf((float)( qsA[j]       & 0xF), ss[j], zs[j]);
            w[2][j] = fmaf((float)((qsB[j] >> 4) & 0xF), ss[j], zs[j]);
            w[3][j] = fmaf((float)( qsB[j]       & 0xF), ss[j], zs[j]);
        }
#pragma unroll
        for (int b = 0; b < 8; ++b) {
            const float4 xb = *(const float4*)(x_lds + b * KC + i);
#pragma unroll
            for (int r = 0; r < 4; ++r) {
                float a = acc[r][b];
                a = fmaf(xb.x, w[r][0], a);
                a = fmaf(xb.y, w[r][1], a);
                a = fmaf(xb.z, w[r][2], a);
                a = fmaf(xb.w, w[r][3], a);
                acc[r][b] = a;
            }
        }
    }

    // ---- reduce across the 64 K-slice lanes ----
#pragma unroll
    for (int r = 0; r < 4; ++r)
#pragma unroll
        for (int b = 0; b < 8; ++b) {
            float v = acc[r][b];
#pragma unroll
            for (int off = 32; off > 0; off >>= 1)
                v += __shfl_down(v, off, 64);
            acc[r][b] = v;
        }

    if (lane == 0) {
        const int o[4] = {rq0 * OC_ + oc, (rq0 + 32) * OC_ + oc,
                          (rq0 + 1) * OC_ + oc, (rq0 + 33) * OC_ + oc};
        float* __restrict__ wp = ws + (long)ks * 8 * OUT_;
#pragma unroll
        for (int r = 0; r < 4; ++r)
#pragma unroll
            for (int b = 0; b < 8; ++b)
                wp[b * OUT_ + o[r]] = acc[r][b];
    }
}

__global__ void hqq_reduce(const float* __restrict__ ws,
                           const float* __restrict__ bias,
                           float* __restrict__ out) {
    const int t = blockIdx.x * 256 + threadIdx.x;
    if (t >= 8 * OUT_) return;
    const int o = t % OUT_;
    float v = bias[o];
#pragma unroll
    for (int k = 0; k < KS; ++k) v += ws[k * 8 * OUT_ + t];
    out[t] = v;
}

extern "C" void kernel_launch(void* const* d_in, const int* in_sizes, int n_in,
                              void* d_out, int out_size, void* d_ws, size_t ws_size,
                              hipStream_t stream) {
    const int*   Wq    = (const int*)d_in[0];    // [32, 704512] int32
    const float* scale = (const float*)d_in[1];  // [1, 704512]
    const float* zero  = (const float*)d_in[2];  // [1, 704512]
    const float* x     = (const float*)d_in[3];  // [8, 1, 4096]
    const float* bias  = (const float*)d_in[4];  // [11008]
    float* out = (float*)d_out;                  // [8, 1, 11008]
    float* ws  = (float*)d_ws;                   // KS*8*11008 floats = 704 KB

    dim3 grid(4, OC_, KS);  // x: rq-group (8 packed rows), y: oc, z: K-split
    dim3 block(64, 4);
    hqq_gemv<<<grid, block, 0, stream>>>(Wq, scale, zero, x, ws);
    hqq_reduce<<<(8 * OUT_ + 255) / 256, 256, 0, stream>>>(ws, bias, out);
}